// Round 3
// baseline (1098.615 us; speedup 1.0000x reference)
//
#include <hip/hip_runtime.h>
#include <hip/hip_bf16.h>

#define N_ROWS 100000
#define F_VS 28
#define HIDN 64
#define OUT_F 768
#define NCLS 4
#define VMAXC 64

#define TILE_BLOCKS 1563            // 1563 * 4 waves = 6252 >= 6250 row-tiles
#define COPY_BLOCKS 485
#define GRID_FUSED (TILE_BLOCKS + COPY_BLOCKS)

#define N4_TOTAL (N_ROWS * OUT_F / 4)   // 19,200,000 float4
#define COPY_A   1572864                // float4 copied in kernel A (48 MB r+w)
#define CHUNKW   16384                  // float4 per stolen wave-chunk (256 iters/lane)

typedef __attribute__((ext_vector_type(8))) short short8;
typedef __attribute__((ext_vector_type(4))) float floatx4;

// ---- workspace layout (bytes) ----
// [0,       28672)  counts  int[256*28]
// [28672,   28688)  class_size int[4]
// [28688,   28692)  copy-chunk steal counter (zeroed by memset)
// [28928,  127232)  wfc bf16 [768*64]

__device__ __forceinline__ float frcp(float x) { return __builtin_amdgcn_rcpf(x); }
__device__ __forceinline__ float sigm(float x) { return frcp(1.f + __expf(-x)); }
__device__ __forceinline__ float tanh_f(float x) { return 1.f - 2.f * frcp(__expf(2.f * x) + 1.f); }

// steal-loop: waves grab CHUNKW-sized copy chunks until exhausted
__device__ __forceinline__ void steal_copy(const float4* __restrict__ CC,
                                           float4* __restrict__ outCC,
                                           int* __restrict__ ctr, int lane) {
    const int nchunks = (N4_TOTAL - COPY_A + CHUNKW - 1) / CHUNKW;
    for (;;) {
        int c = 0;
        if (lane == 0) c = atomicAdd(ctr, 1);
        c = __shfl(c, 0);
        if (c >= nchunks) break;
        int base = COPY_A + c * CHUNKW;
        int end = base + CHUNKW;
        if (end > N4_TOTAL) end = N4_TOTAL;
        for (int i = base + lane; i < end; i += 64) outCC[i] = CC[i];
    }
}

// Kernel A: histogram (blocks 0..63) + W_fc->bf16 + first slice of CC copy (blocks 64..255)
__global__ __launch_bounds__(256) void k_hist(const float* __restrict__ VS,
                                              const int* __restrict__ Level,
                                              const float* __restrict__ Wfc,
                                              int* __restrict__ counts,
                                              int* __restrict__ cls,
                                              __hip_bfloat16* __restrict__ wfc16,
                                              const float4* __restrict__ CC,
                                              float4* __restrict__ outCC) {
    int tid = threadIdx.x;
    int b = blockIdx.x;

    // W_fc fp32 -> bf16 spread over all 256 blocks (49152 elems)
    {
        int gtid = b * 256 + tid;
        int gsz = 256 * 256;
        for (int i = gtid; i < OUT_F * HIDN; i += gsz)
            wfc16[i] = __float2bfloat16(Wfc[i]);
    }

    if (b >= 64) {
        // ---- copy role: first COPY_A float4 of CC ----
        int ctid = (b - 64) * 256 + tid;
        int csz = 192 * 256;
        for (int i = ctid; i < COPY_A; i += csz) outCC[i] = CC[i];
        return;
    }

    // ---- hist role (identical to verified version) ----
    __shared__ int lc[NCLS * VMAXC * F_VS];   // 7168 ints = 28 KB
    __shared__ int lcls[NCLS];
    for (int i = tid; i < NCLS * VMAXC * F_VS; i += 256) lc[i] = 0;
    if (tid < NCLS) lcls[tid] = 0;
    __syncthreads();

    int gtid = b * 256 + tid;
    int gsz = 64 * 256;
    for (int i = gtid; i < N_ROWS; i += gsz) {
        int lab = Level[i];
        atomicAdd(&lcls[lab], 1);
        const float4* row = (const float4*)(VS + (size_t)i * F_VS);  // 112B rows, 16B aligned
#pragma unroll
        for (int q = 0; q < 7; q++) {
            float4 v4 = row[q];
            int c = q * 4;
            atomicAdd(&lc[((lab << 6) + (int)v4.x) * F_VS + c + 0], 1);
            atomicAdd(&lc[((lab << 6) + (int)v4.y) * F_VS + c + 1], 1);
            atomicAdd(&lc[((lab << 6) + (int)v4.z) * F_VS + c + 2], 1);
            atomicAdd(&lc[((lab << 6) + (int)v4.w) * F_VS + c + 3], 1);
        }
    }
    __syncthreads();
    for (int i = tid; i < NCLS * VMAXC * F_VS; i += 256) {
        int v = lc[i];
        if (v) atomicAdd(&counts[i], v);
    }
    if (tid < NCLS) {
        int v = lcls[tid];
        if (v) atomicAdd(&cls[tid], v);
    }
}

// Kernel B (fused): casual-weight + LSTM -> h in LDS -> MFMA gemm -> vs_feat;
// copy blocks + finished tile blocks work-steal the remaining CC copy.
__global__ __launch_bounds__(256) void k_fused(const float* __restrict__ VS,
                                               const int* __restrict__ Level,
                                               const int* __restrict__ Depart,
                                               const float* __restrict__ Wih,
                                               const float* __restrict__ bih,
                                               const float* __restrict__ bhh,
                                               const int* __restrict__ counts,
                                               const int* __restrict__ cls,
                                               const __hip_bfloat16* __restrict__ wfc16,
                                               const float* __restrict__ bfc,
                                               const float4* __restrict__ CC,
                                               float4* __restrict__ outCC,
                                               float* __restrict__ outV,
                                               float* __restrict__ outL,
                                               float* __restrict__ outD,
                                               int* __restrict__ ctr) {
    int tid = threadIdx.x;
    int lane = tid & 63;

    if (blockIdx.x >= TILE_BLOCKS) {
        // ---- copy role: Level/Depart passthrough, then steal copy chunks ----
        int cb = blockIdx.x - TILE_BLOCKS;
        int ctid = cb * 256 + tid;
        int csz = COPY_BLOCKS * 256;
        for (int i = ctid; i < N_ROWS; i += csz) {
            outL[i] = (float)Level[i];
            outD[i] = (float)Depart[i];
        }
        steal_copy(CC, outCC, ctr, lane);
        return;
    }

    // ---- tile role: one wave owns one 16-row tile ----
    int wib = tid >> 6;
    int wave = blockIdx.x * 4 + wib;
    const int nm = N_ROWS / 16;  // 6250 exact

    __shared__ float xsh[4][64];       // one row per wave; broadcast reads
    __shared__ short hsh[4][16][72];   // h tile, bf16 bits; stride 72 -> 2-way alias only

    if (wave < nm) {
        // torch gate order i,f,g,o -> rows {lane, 128+lane, 192+lane} of W_ih (f dead)
        float w0[F_VS], w2[F_VS], w3[F_VS];
#pragma unroll
        for (int j = 0; j < F_VS; j++) {
            w0[j] = Wih[(0 * HIDN + lane) * F_VS + j];
            w2[j] = Wih[(2 * HIDN + lane) * F_VS + j];
            w3[j] = Wih[(3 * HIDN + lane) * F_VS + j];
        }
        float b0 = bih[0 * HIDN + lane] + bhh[0 * HIDN + lane];
        float b2 = bih[2 * HIDN + lane] + bhh[2 * HIDN + lane];
        float b3 = bih[3 * HIDN + lane] + bhh[3 * HIDN + lane];

        int row0 = wave * 16;
#pragma unroll 1
        for (int i = 0; i < 16; i++) {
            int r = row0 + i;
            int lab = Level[r];
            float inv = frcp((float)cls[lab]);
            float xv = 0.f;
            if (lane < F_VS) {
                float v = VS[(size_t)r * F_VS + lane];
                int vi = (int)v;
                int cnt = counts[(((lab << 6) | vi)) * F_VS + lane];
                xv = v * ((float)cnt * inv);
            }
            xsh[wib][lane] = xv;               // all 64 lanes write (28..63 write 0)
            __asm__ volatile("" ::: "memory"); // keep ds_write before ds_reads

            float a0 = b0, a2 = b2, a3 = b3;
#pragma unroll
            for (int q = 0; q < 7; q++) {
                floatx4 xq = *(const floatx4*)(&xsh[wib][q * 4]);
                a0 = fmaf(xq[0], w0[4 * q + 0], a0);
                a0 = fmaf(xq[1], w0[4 * q + 1], a0);
                a0 = fmaf(xq[2], w0[4 * q + 2], a0);
                a0 = fmaf(xq[3], w0[4 * q + 3], a0);
                a2 = fmaf(xq[0], w2[4 * q + 0], a2);
                a2 = fmaf(xq[1], w2[4 * q + 1], a2);
                a2 = fmaf(xq[2], w2[4 * q + 2], a2);
                a2 = fmaf(xq[3], w2[4 * q + 3], a2);
                a3 = fmaf(xq[0], w3[4 * q + 0], a3);
                a3 = fmaf(xq[1], w3[4 * q + 1], a3);
                a3 = fmaf(xq[2], w3[4 * q + 2], a3);
                a3 = fmaf(xq[3], w3[4 * q + 3], a3);
            }
            __asm__ volatile("" ::: "memory"); // don't sink next ds_write above reads

            float c = sigm(a0) * tanh_f(a2);
            float h = sigm(a3) * tanh_f(c);
            __hip_bfloat16 hb = __float2bfloat16(h);
            hsh[wib][i][lane] = *(short*)&hb;
        }
        __asm__ volatile("" ::: "memory");     // h tile writes before A-frag reads

        // ---- gemm: A = h tile (LDS), B = W_fc^T (cache-resident 96KB) ----
        int quad = lane >> 4;    // 0..3
        int l16 = lane & 15;
        const short* hA = &hsh[wib][l16][quad * 8];
        short8 a0v = *(const short8*)(hA);
        short8 a1v = *(const short8*)(hA + 32);

        for (int nt = 0; nt < OUT_F / 16; nt++) {
            const short* pB = (const short*)(wfc16 + (size_t)(nt * 16 + l16) * HIDN + quad * 8);
            short8 bf0 = *(const short8*)(pB);
            short8 bf1 = *(const short8*)(pB + 32);
            floatx4 acc = {0.f, 0.f, 0.f, 0.f};
            acc = __builtin_amdgcn_mfma_f32_16x16x32_bf16(a0v, bf0, acc, 0, 0, 0);
            acc = __builtin_amdgcn_mfma_f32_16x16x32_bf16(a1v, bf1, acc, 0, 0, 0);
            float bias = bfc[nt * 16 + l16];
            // C: col = lane&15, row = quad*4 + reg
#pragma unroll
            for (int rr = 0; rr < 4; rr++) {
                outV[(size_t)(row0 + quad * 4 + rr) * OUT_F + nt * 16 + l16] = acc[rr] + bias;
            }
        }
    }

    // ---- tile waves done: join the copy steal loop ----
    steal_copy(CC, outCC, ctr, lane);
}

extern "C" void kernel_launch(void* const* d_in, const int* in_sizes, int n_in,
                              void* d_out, int out_size, void* d_ws, size_t ws_size,
                              hipStream_t stream) {
    const float* VS = (const float*)d_in[0];
    const float* CC = (const float*)d_in[1];
    const int* Level = (const int*)d_in[2];
    const int* Depart = (const int*)d_in[3];
    const float* Wih = (const float*)d_in[4];
    // d_in[5] = W_hh unused (h0 = 0)
    const float* bih = (const float*)d_in[6];
    const float* bhh = (const float*)d_in[7];
    const float* Wfc = (const float*)d_in[8];
    const float* bfc = (const float*)d_in[9];

    float* out = (float*)d_out;
    char* ws = (char*)d_ws;
    int* counts = (int*)ws;
    int* cls = (int*)(ws + 28672);
    int* ctr = (int*)(ws + 28688);
    __hip_bfloat16* wfc16 = (__hip_bfloat16*)(ws + 28928);

    float* outCC = out;
    float* outV = out + (size_t)N_ROWS * OUT_F;
    float* outL = out + (size_t)2 * N_ROWS * OUT_F;
    float* outD = outL + N_ROWS;

    hipMemsetAsync(d_ws, 0, 28692, stream);  // zero counts + class_size + steal counter
    k_hist<<<256, 256, 0, stream>>>(VS, Level, Wfc, counts, cls, wfc16,
                                    (const float4*)CC, (float4*)outCC);
    k_fused<<<GRID_FUSED, 256, 0, stream>>>(VS, Level, Depart, Wih, bih, bhh,
                                            counts, cls, wfc16, bfc,
                                            (const float4*)CC, (float4*)outCC,
                                            outV, outL, outD, ctr);
}